// Round 1
// baseline (213.943 us; speedup 1.0000x reference)
//
#include <hip/hip_runtime.h>
#include <hip/hip_bf16.h>

typedef __attribute__((ext_vector_type(8))) __bf16 bf16x8;
typedef __attribute__((ext_vector_type(4))) float f32x4;
typedef unsigned short u16;

#define BATCH 8
#define CIN   62
#define HW    224
#define NPIX  49

__device__ __forceinline__ u16 f2b(float f) {
    union { __hip_bfloat16 h; u16 u; } cv;
    cv.h = __float2bfloat16(f);
    return cv.u;
}

// LDS 64x64 bf16 tiles, row stride 64 elems (128B), XOR swizzle on 8-elem (16B) blocks
__device__ __forceinline__ bf16x8 ld8(const u16* buf, int row, int ecol) {
    int idx = (row << 6) + (ecol ^ ((row & 7) << 3));
    return *reinterpret_cast<const bf16x8*>(buf + idx);
}
__device__ __forceinline__ void st1(u16* buf, int row, int ecol, u16 v) {
    buf[(row << 6) + (ecol ^ ((row & 7) << 3))] = v;
}
__device__ __forceinline__ void st4(u16* buf, int row, int ecol, u16 a, u16 b, u16 c, u16 d) {
    int idx = (row << 6) + (ecol ^ ((row & 7) << 3));
    *reinterpret_cast<ushort4*>(buf + idx) = make_ushort4(a, b, c, d);
}

__global__ void prep_weights(const float* __restrict__ wq, const float* __restrict__ wp,
                             u16* __restrict__ wq_b, u16* __restrict__ wp_b) {
    int t = blockIdx.x * 256 + threadIdx.x;
    if (t < 192 * 64) wq_b[t] = f2b(wq[t]);
    if (t < 64 * 64) {
        int co = t >> 6, c = t & 63;
        wp_b[t] = (co < CIN) ? f2b(wp[co * 64 + c]) : (u16)0;
    }
}

__global__ __launch_bounds__(256) void win_attn(
    const float* __restrict__ x, const u16* __restrict__ wq_b,
    const u16* __restrict__ wp_b, const float* __restrict__ bproj,
    float* __restrict__ out)
{
    __shared__ __align__(16) u16 t0[64 * 64];  // XT[p][c]  -> later P[i][j]
    __shared__ __align__(16) u16 t1[64 * 64];  // qT[p][c]  -> later outT[i][c]
    __shared__ __align__(16) u16 t2[64 * 64];  // kT[p][c]
    __shared__ __align__(16) u16 t3[64 * 64];  // v[c][p]
    __shared__ float Sm[64 * 65];
    __shared__ float mrow[64];
    __shared__ float sinv[64];

    const int tid  = threadIdx.x;
    const int lane = tid & 63;
    const int wid  = tid >> 6;
    const int lr   = lane & 15;  // col within 16x16 D tile / row within frag
    const int lg   = lane >> 4;  // k-group / row-group

    const int win = blockIdx.x;
    const int b   = win >> 10;
    const int rem = win & 1023;
    const int hn  = rem >> 5;
    const int wn  = rem & 31;
    const int h0  = hn * 7, w0 = wn * 7;

    // ---- stage XT[p][c] bf16 (rows p>=49 zero; c=62,63 are coord channels)
    for (int idx = tid; idx < 64 * 64; idx += 256) {
        int p = idx & 63;
        int c = idx >> 6;
        float v = 0.0f;
        if (p < NPIX) {
            int dh = p / 7;
            int dw = p - dh * 7;
            int h = h0 + dh, w = w0 + dw;
            if (c < CIN)      v = x[((b * CIN + c) * HW + h) * HW + w];
            else if (c == 62) v = -1.0f + (2.0f / 223.0f) * (float)w;
            else              v = -1.0f + (2.0f / 223.0f) * (float)h;
        }
        st1(t0, p, c, f2b(v));
    }
    __syncthreads();

    const f32x4 fz = {0.f, 0.f, 0.f, 0.f};

    // ---- QKV(192x64-pix) = Wq(192x64ch) @ X ; wave handles M-tiles wid*3..wid*3+2
    f32x4 acc[3][4];
#pragma unroll
    for (int m = 0; m < 3; ++m)
#pragma unroll
        for (int n = 0; n < 4; ++n) acc[m][n] = fz;

#pragma unroll
    for (int ks = 0; ks < 2; ++ks) {
        bf16x8 a[3];
#pragma unroll
        for (int m = 0; m < 3; ++m) {
            int o = (wid * 3 + m) * 16 + lr;
            a[m] = *reinterpret_cast<const bf16x8*>(wq_b + o * 64 + ks * 32 + lg * 8);
        }
#pragma unroll
        for (int n = 0; n < 4; ++n) {
            bf16x8 bb = ld8(t0, n * 16 + lr, ks * 32 + lg * 8);
#pragma unroll
            for (int m = 0; m < 3; ++m)
                acc[m][n] = __builtin_amdgcn_mfma_f32_16x16x32_bf16(a[m], bb, acc[m][n], 0, 0, 0);
        }
    }

    // scatter: q -> t1 transposed [p][c], k -> t2 transposed [p][c], v -> t3 natural [c][p]
#pragma unroll
    for (int m = 0; m < 3; ++m) {
        int mt = wid * 3 + m;
#pragma unroll
        for (int n = 0; n < 4; ++n) {
            int p = n * 16 + lr;
            if (mt < 8) {
                u16* dst = (mt < 4) ? t1 : t2;
                int cb = (mt & 3) * 16 + lg * 4;
                st4(dst, p, cb, f2b(acc[m][n][0]), f2b(acc[m][n][1]),
                                f2b(acc[m][n][2]), f2b(acc[m][n][3]));
            } else {
                int cb = (mt - 8) * 16 + lg * 4;
#pragma unroll
                for (int r = 0; r < 4; ++r)
                    st1(t3, cb + r, p, f2b(acc[m][n][r]));
            }
        }
    }
    __syncthreads();

    // ---- S[i][j] = sum_c q[c,i]*k[c,j] * 0.125 ; wave -> M-tile wid
    f32x4 acc2[4];
#pragma unroll
    for (int n = 0; n < 4; ++n) acc2[n] = fz;
#pragma unroll
    for (int ks = 0; ks < 2; ++ks) {
        bf16x8 aq = ld8(t1, wid * 16 + lr, ks * 32 + lg * 8);
#pragma unroll
        for (int n = 0; n < 4; ++n) {
            bf16x8 bk = ld8(t2, n * 16 + lr, ks * 32 + lg * 8);
            acc2[n] = __builtin_amdgcn_mfma_f32_16x16x32_bf16(aq, bk, acc2[n], 0, 0, 0);
        }
    }
#pragma unroll
    for (int n = 0; n < 4; ++n)
#pragma unroll
        for (int r = 0; r < 4; ++r) {
            int i = wid * 16 + lg * 4 + r;
            int j = n * 16 + lr;
            Sm[i * 65 + j] = acc2[n][r] * 0.125f;
        }
    __syncthreads();

    // ---- softmax stats: 4 lanes per row (rows 0..48)
    if (tid < 196) {
        int row = tid >> 2, part = tid & 3;
        int j0 = part * 13;
        int j1 = (j0 + 13 < NPIX) ? j0 + 13 : NPIX;
        float mx = -1e30f;
        for (int j = j0; j < j1; ++j) mx = fmaxf(mx, Sm[row * 65 + j]);
        mx = fmaxf(mx, __shfl_xor(mx, 1));
        mx = fmaxf(mx, __shfl_xor(mx, 2));
        float sm = 0.f;
        for (int j = j0; j < j1; ++j) sm += __expf(Sm[row * 65 + j] - mx);
        sm += __shfl_xor(sm, 1);
        sm += __shfl_xor(sm, 2);
        if (part == 0) { mrow[row] = mx; sinv[row] = 1.0f / sm; }
    }
    __syncthreads();

    // ---- write P[i][j] bf16 into t0 (zeros in the 49..63 pad keep PV exact)
    for (int idx = tid; idx < 64 * 64; idx += 256) {
        int i = idx >> 6, j = idx & 63;
        float pv = 0.f;
        if (i < NPIX && j < NPIX)
            pv = __expf(Sm[i * 65 + j] - mrow[i]) * sinv[i];
        st1(t0, i, j, f2b(pv));
    }
    __syncthreads();

    // ---- OUT[c][i] = sum_j v[c][j] * P[i][j] ; wave -> M-tile wid (c-range)
    f32x4 acc3[4];
#pragma unroll
    for (int n = 0; n < 4; ++n) acc3[n] = fz;
#pragma unroll
    for (int ks = 0; ks < 2; ++ks) {
        bf16x8 av = ld8(t3, wid * 16 + lr, ks * 32 + lg * 8);
#pragma unroll
        for (int n = 0; n < 4; ++n) {
            bf16x8 bp = ld8(t0, n * 16 + lr, ks * 32 + lg * 8);
            acc3[n] = __builtin_amdgcn_mfma_f32_16x16x32_bf16(av, bp, acc3[n], 0, 0, 0);
        }
    }
    // write outT[i][c] into t1 (t1's qT was last read before 2 barriers ago)
#pragma unroll
    for (int n = 0; n < 4; ++n) {
        int i = n * 16 + lr;
        int cb = wid * 16 + lg * 4;
        st4(t1, i, cb, f2b(acc3[n][0]), f2b(acc3[n][1]), f2b(acc3[n][2]), f2b(acc3[n][3]));
    }
    __syncthreads();

    // ---- Y[co][p] = sum_c wp[co][c] * out[c][p] + bias
    f32x4 acc4[4];
#pragma unroll
    for (int n = 0; n < 4; ++n) acc4[n] = fz;
#pragma unroll
    for (int ks = 0; ks < 2; ++ks) {
        bf16x8 aw = *reinterpret_cast<const bf16x8*>(wp_b + (wid * 16 + lr) * 64 + ks * 32 + lg * 8);
#pragma unroll
        for (int n = 0; n < 4; ++n) {
            bf16x8 bo = ld8(t1, n * 16 + lr, ks * 32 + lg * 8);
            acc4[n] = __builtin_amdgcn_mfma_f32_16x16x32_bf16(aw, bo, acc4[n], 0, 0, 0);
        }
    }

    const int cb = wid * 16 + lg * 4;
    float bias[4];
#pragma unroll
    for (int r = 0; r < 4; ++r) bias[r] = (cb + r < CIN) ? bproj[cb + r] : 0.f;
#pragma unroll
    for (int n = 0; n < 4; ++n) {
        int p = n * 16 + lr;
        if (p < NPIX) {
            int dh = p / 7, dw = p - dh * 7;
            int h = h0 + dh, w = w0 + dw;
#pragma unroll
            for (int r = 0; r < 4; ++r) {
                int co = cb + r;
                if (co < CIN)
                    out[((b * CIN + co) * HW + h) * HW + w] = acc4[n][r] + bias[r];
            }
        }
    }
}

extern "C" void kernel_launch(void* const* d_in, const int* in_sizes, int n_in,
                              void* d_out, int out_size, void* d_ws, size_t ws_size,
                              hipStream_t stream) {
    const float* x  = (const float*)d_in[0];
    const float* wq = (const float*)d_in[1];
    const float* wp = (const float*)d_in[2];
    const float* bp = (const float*)d_in[3];
    float* out = (float*)d_out;

    u16* wq_b = (u16*)d_ws;             // 192*64 bf16
    u16* wp_b = wq_b + 192 * 64;        // 64*64 bf16 (rows 62,63 zero)

    prep_weights<<<48, 256, 0, stream>>>(wq, wp, wq_b, wp_b);
    win_attn<<<8192, 256, 0, stream>>>(x, wq_b, wp_b, bp, out);
}

// Round 2
// 139.241 us; speedup vs baseline: 1.5365x; 1.5365x over previous
//
#include <hip/hip_runtime.h>
#include <hip/hip_bf16.h>

typedef __attribute__((ext_vector_type(8))) __bf16 bf16x8;
typedef __attribute__((ext_vector_type(4))) float f32x4;
typedef unsigned short u16;

#define CIN   62
#define HW    224
#define NPIX  49

__device__ __forceinline__ u16 f2b(float f) {
    union { __hip_bfloat16 h; u16 u; } cv;
    cv.h = __float2bfloat16(f);
    return cv.u;
}

// LDS 64x64 bf16 tiles, row stride 64 elems (128B), XOR swizzle on 8-elem (16B) blocks
__device__ __forceinline__ bf16x8 ld8(const u16* buf, int row, int ecol) {
    int idx = (row << 6) + (ecol ^ ((row & 7) << 3));
    return *reinterpret_cast<const bf16x8*>(buf + idx);
}
__device__ __forceinline__ void st1(u16* buf, int row, int ecol, u16 v) {
    buf[(row << 6) + (ecol ^ ((row & 7) << 3))] = v;
}
__device__ __forceinline__ void st4(u16* buf, int row, int ecol, u16 a, u16 b, u16 c, u16 d) {
    int idx = (row << 6) + (ecol ^ ((row & 7) << 3));
    *reinterpret_cast<ushort4*>(buf + idx) = make_ushort4(a, b, c, d);
}

// Build bf16 weight matrix: rows 0..63 = Wq, 64..127 = Wk, 128..191 = Wfuse = Wp @ Wv
// (Y = Wp (V P^T) = (Wp Wv X) P^T, so V never needs materializing)
__global__ void prep_weights(const float* __restrict__ wqkv, const float* __restrict__ wp,
                             u16* __restrict__ wb) {
    int t = blockIdx.x * 256 + threadIdx.x;   // 0 .. 192*64-1
    if (t < 128 * 64) {
        wb[t] = f2b(wqkv[t]);
    } else if (t < 192 * 64) {
        int o = (t - 128 * 64) >> 6;          // fused output channel 0..63
        int c = t & 63;
        float s = 0.0f;
        if (o < CIN) {
            for (int m = 0; m < 64; ++m)
                s += wp[o * 64 + m] * wqkv[(128 + m) * 64 + c];
        }
        wb[t] = f2b(s);
    }
}

__global__ __launch_bounds__(256, 5) void win_attn(
    const float* __restrict__ x, const u16* __restrict__ wb,
    const float* __restrict__ bproj, float* __restrict__ out)
{
    __shared__ __align__(16) u16 t0[64 * 64];  // XT[p][c]  -> later P[i][j]
    __shared__ __align__(16) u16 t1[64 * 64];  // qT[p][c]
    __shared__ __align__(16) u16 t2[64 * 64];  // kT[p][c]
    __shared__ __align__(16) u16 t4[64 * 64];  // F[co][j] = (Wp Wv X)

    const int tid  = threadIdx.x;
    const int lane = tid & 63;
    const int wid  = tid >> 6;
    const int lr   = lane & 15;
    const int lg   = lane >> 4;

    // XCD swizzle: each XCD gets a contiguous run of 1024 windows (one batch image)
    const int win = ((blockIdx.x & 7) << 10) | (blockIdx.x >> 3);
    const int b   = win >> 10;
    const int rem = win & 1023;
    const int hn  = rem >> 5;
    const int wn  = rem & 31;
    const int h0  = hn * 7, w0 = wn * 7;

    // ---- stage XT[p][c] bf16 (rows p>=49 zero; c=62,63 coord channels)
    for (int idx = tid; idx < 64 * 64; idx += 256) {
        int p = idx & 63;
        int c = idx >> 6;
        float v = 0.0f;
        if (p < NPIX) {
            int dh = p / 7;
            int dw = p - dh * 7;
            int h = h0 + dh, w = w0 + dw;
            if (c < CIN)      v = x[((b * CIN + c) * HW + h) * HW + w];
            else if (c == 62) v = -1.0f + (2.0f / 223.0f) * (float)w;
            else              v = -1.0f + (2.0f / 223.0f) * (float)h;
        }
        st1(t0, p, c, f2b(v));
    }
    __syncthreads();

    const f32x4 fz = {0.f, 0.f, 0.f, 0.f};

    // ---- [q;k;F](192 x 64pix) = Wb(192x64ch) @ X ; wave -> M-tiles wid*3..+2
    f32x4 acc[3][4];
#pragma unroll
    for (int m = 0; m < 3; ++m)
#pragma unroll
        for (int n = 0; n < 4; ++n) acc[m][n] = fz;

#pragma unroll
    for (int ks = 0; ks < 2; ++ks) {
        bf16x8 a[3];
#pragma unroll
        for (int m = 0; m < 3; ++m) {
            int o = (wid * 3 + m) * 16 + lr;
            a[m] = *reinterpret_cast<const bf16x8*>(wb + o * 64 + ks * 32 + lg * 8);
        }
#pragma unroll
        for (int n = 0; n < 4; ++n) {
            bf16x8 bb = ld8(t0, n * 16 + lr, ks * 32 + lg * 8);
#pragma unroll
            for (int m = 0; m < 3; ++m)
                acc[m][n] = __builtin_amdgcn_mfma_f32_16x16x32_bf16(a[m], bb, acc[m][n], 0, 0, 0);
        }
    }

    // scatter: q -> t1 [p][c], k -> t2 [p][c], F -> t4 [co][j]
#pragma unroll
    for (int m = 0; m < 3; ++m) {
        int mt = wid * 3 + m;
#pragma unroll
        for (int n = 0; n < 4; ++n) {
            int p = n * 16 + lr;   // D col index = pixel
            if (mt < 8) {
                u16* dst = (mt < 4) ? t1 : t2;
                int cb = (mt & 3) * 16 + lg * 4;
                st4(dst, p, cb, f2b(acc[m][n][0]), f2b(acc[m][n][1]),
                                f2b(acc[m][n][2]), f2b(acc[m][n][3]));
            } else {
                int co_b = (mt - 8) * 16 + lg * 4;
#pragma unroll
                for (int r = 0; r < 4; ++r)
                    st1(t4, co_b + r, p, f2b(acc[m][n][r]));
            }
        }
    }
    __syncthreads();

    // ---- S[i][j] = sum_c q[c,i] k[c,j] * 0.125 ; wave -> M-tile wid
    f32x4 s4[4];
#pragma unroll
    for (int n = 0; n < 4; ++n) s4[n] = fz;
#pragma unroll
    for (int ks = 0; ks < 2; ++ks) {
        bf16x8 aq = ld8(t1, wid * 16 + lr, ks * 32 + lg * 8);
#pragma unroll
        for (int n = 0; n < 4; ++n) {
            bf16x8 bk = ld8(t2, n * 16 + lr, ks * 32 + lg * 8);
            s4[n] = __builtin_amdgcn_mfma_f32_16x16x32_bf16(aq, bk, s4[n], 0, 0, 0);
        }
    }

    // ---- register softmax: row i lives in the 16-lane lr group (4 vals/lane across n)
#pragma unroll
    for (int r = 0; r < 4; ++r) {
        const int i = wid * 16 + lg * 4 + r;
        float v[4], mx = -1e30f;
#pragma unroll
        for (int n = 0; n < 4; ++n) {
            v[n] = s4[n][r] * 0.125f;
            int j = n * 16 + lr;
            mx = fmaxf(mx, (j < NPIX) ? v[n] : -1e30f);
        }
        mx = fmaxf(mx, __shfl_xor(mx, 1));
        mx = fmaxf(mx, __shfl_xor(mx, 2));
        mx = fmaxf(mx, __shfl_xor(mx, 4));
        mx = fmaxf(mx, __shfl_xor(mx, 8));
        float e[4], sm = 0.f;
#pragma unroll
        for (int n = 0; n < 4; ++n) {
            int j = n * 16 + lr;
            e[n] = (j < NPIX) ? __expf(v[n] - mx) : 0.f;
            sm += e[n];
        }
        sm += __shfl_xor(sm, 1);
        sm += __shfl_xor(sm, 2);
        sm += __shfl_xor(sm, 4);
        sm += __shfl_xor(sm, 8);
        float sinv = 1.0f / sm;
#pragma unroll
        for (int n = 0; n < 4; ++n)
            st1(t0, i, n * 16 + lr, f2b(e[n] * sinv));
    }
    __syncthreads();

    // ---- Y[co][p] = sum_j F[co][j] P[p][j] ; wave -> M-tile wid (co range)
    f32x4 y4[4];
#pragma unroll
    for (int n = 0; n < 4; ++n) y4[n] = fz;
#pragma unroll
    for (int ks = 0; ks < 2; ++ks) {
        bf16x8 af = ld8(t4, wid * 16 + lr, ks * 32 + lg * 8);
#pragma unroll
        for (int n = 0; n < 4; ++n) {
            bf16x8 bp = ld8(t0, n * 16 + lr, ks * 32 + lg * 8);
            y4[n] = __builtin_amdgcn_mfma_f32_16x16x32_bf16(af, bp, y4[n], 0, 0, 0);
        }
    }

    const int cb = wid * 16 + lg * 4;
    float bias[4];
#pragma unroll
    for (int r = 0; r < 4; ++r) bias[r] = (cb + r < CIN) ? bproj[cb + r] : 0.f;
#pragma unroll
    for (int n = 0; n < 4; ++n) {
        int p = n * 16 + lr;
        if (p < NPIX) {
            int dh = p / 7, dw = p - dh * 7;
            int h = h0 + dh, w = w0 + dw;
#pragma unroll
            for (int r = 0; r < 4; ++r) {
                int co = cb + r;
                if (co < CIN)
                    out[((b * CIN + co) * HW + h) * HW + w] = y4[n][r] + bias[r];
            }
        }
    }
}

extern "C" void kernel_launch(void* const* d_in, const int* in_sizes, int n_in,
                              void* d_out, int out_size, void* d_ws, size_t ws_size,
                              hipStream_t stream) {
    const float* x    = (const float*)d_in[0];
    const float* wqkv = (const float*)d_in[1];
    const float* wp   = (const float*)d_in[2];
    const float* bp   = (const float*)d_in[3];
    float* out = (float*)d_out;

    u16* wb = (u16*)d_ws;   // 192*64 bf16: [Wq; Wk; Wp@Wv]

    prep_weights<<<48, 256, 0, stream>>>(wqkv, wp, wb);
    win_attn<<<8192, 256, 0, stream>>>(x, wb, bp, out);
}

// Round 3
// 95.765 us; speedup vs baseline: 2.2340x; 1.4540x over previous
//
#include <hip/hip_runtime.h>
#include <hip/hip_bf16.h>

typedef __attribute__((ext_vector_type(8))) __bf16 bf16x8;
typedef __attribute__((ext_vector_type(4))) float f32x4;
typedef unsigned short u16;

#define CIN   62
#define HW    224
#define NPIX  49

__device__ __forceinline__ u16 f2b(float f) {
    union { __hip_bfloat16 h; u16 u; } cv;
    cv.h = __float2bfloat16(f);
    return cv.u;
}

// LDS 64x64 bf16 tiles, row stride 64 elems (128B), XOR swizzle on 8-elem (16B) blocks
__device__ __forceinline__ bf16x8 ld8(const u16* buf, int row, int ecol) {
    int idx = (row << 6) + (ecol ^ ((row & 7) << 3));
    return *reinterpret_cast<const bf16x8*>(buf + idx);
}
__device__ __forceinline__ void st1(u16* buf, int row, int ecol, u16 v) {
    buf[(row << 6) + (ecol ^ ((row & 7) << 3))] = v;
}
__device__ __forceinline__ void st4(u16* buf, int row, int ecol, u16 a, u16 b, u16 c, u16 d) {
    int idx = (row << 6) + (ecol ^ ((row & 7) << 3));
    *reinterpret_cast<ushort4*>(buf + idx) = make_ushort4(a, b, c, d);
}

// wb rows 0..63  = G  = Wq^T Wk / 8   (S = X^T G X)
// wb rows 64..127 = Wf = Wp @ Wv      (Y = Wf X P^T)
__global__ void prep_weights(const float* __restrict__ wqkv, const float* __restrict__ wp,
                             u16* __restrict__ wb) {
    int t = blockIdx.x * 256 + threadIdx.x;   // 0 .. 128*64-1
    if (t >= 128 * 64) return;
    int o = t >> 6;       // row
    int c = t & 63;       // col
    float s = 0.0f;
    if (o < 64) {
        // G[o][c] = sum_m Wq[m][o] * Wk[m][c] / 8
        for (int m = 0; m < 64; ++m)
            s += wqkv[m * 64 + o] * wqkv[(64 + m) * 64 + c];
        s *= 0.125f;
    } else {
        int of = o - 64;
        if (of < CIN)
            for (int m = 0; m < 64; ++m)
                s += wp[of * 64 + m] * wqkv[(128 + m) * 64 + c];
    }
    wb[t] = f2b(s);
}

__global__ __launch_bounds__(256, 6) void win_attn(
    const float* __restrict__ x, const u16* __restrict__ wb,
    const float* __restrict__ bproj, float* __restrict__ out)
{
    __shared__ __align__(16) u16 t0[64 * 64];  // XT[p][c]  -> later P[i][j]
    __shared__ __align__(16) u16 t1[64 * 64];  // T[j][g] (transposed G@X)
    __shared__ __align__(16) u16 t2[64 * 64];  // F[co][j]

    const int tid  = threadIdx.x;
    const int lane = tid & 63;
    const int wid  = tid >> 6;
    const int lr   = lane & 15;
    const int lg   = lane >> 4;

    // XCD swizzle: each XCD gets one batch image (1024 consecutive windows)
    const int win = ((blockIdx.x & 7) << 10) | (blockIdx.x >> 3);
    const int b   = win >> 10;
    const int rem = win & 1023;
    const int hn  = rem >> 5;
    const int wn  = rem & 31;
    const int h0  = hn * 7, w0 = wn * 7;

    // ---- stage XT[p][c] bf16 (rows p>=49 zero; c=62,63 coord channels)
    {
        const int p = tid & 63;
        const bool valid = p < NPIX;
        const int dh = p / 7, dw = p - dh * 7;
        const int h = h0 + dh, w = w0 + dw;
        const float cx = -1.0f + (2.0f / 223.0f) * (float)w;
        const float cy = -1.0f + (2.0f / 223.0f) * (float)h;
        const float* xp = x + (size_t)b * CIN * HW * HW + (size_t)h * HW + w;
#pragma unroll
        for (int it = 0; it < 16; ++it) {
            int c = (tid >> 6) + it * 4;
            float v = 0.0f;
            if (valid) {
                if (c < CIN)      v = xp[(size_t)c * HW * HW];
                else if (c == 62) v = cx;
                else              v = cy;
            }
            st1(t0, p, c, f2b(v));
        }
    }
    __syncthreads();

    const f32x4 fz = {0.f, 0.f, 0.f, 0.f};

    // ---- GEMM1: [T; F](128 x 64px) = wb(128x64ch) @ X ; wave -> M-tiles wid*2, wid*2+1
    f32x4 acc[2][4];
#pragma unroll
    for (int m = 0; m < 2; ++m)
#pragma unroll
        for (int n = 0; n < 4; ++n) acc[m][n] = fz;

#pragma unroll
    for (int ks = 0; ks < 2; ++ks) {
        bf16x8 a[2];
#pragma unroll
        for (int m = 0; m < 2; ++m) {
            int o = (wid * 2 + m) * 16 + lr;
            a[m] = *reinterpret_cast<const bf16x8*>(wb + o * 64 + ks * 32 + lg * 8);
        }
#pragma unroll
        for (int n = 0; n < 4; ++n) {
            bf16x8 bb = ld8(t0, n * 16 + lr, ks * 32 + lg * 8);
#pragma unroll
            for (int m = 0; m < 2; ++m)
                acc[m][n] = __builtin_amdgcn_mfma_f32_16x16x32_bf16(a[m], bb, acc[m][n], 0, 0, 0);
        }
    }

    // scatter: T (mt<4) -> t1[j][g] transposed-by-st4 ; F (mt>=4) -> t2[co][j]
#pragma unroll
    for (int m = 0; m < 2; ++m) {
        int mt = wid * 2 + m;
#pragma unroll
        for (int n = 0; n < 4; ++n) {
            int j = n * 16 + lr;   // D col = pixel
            if (mt < 4) {
                int gb = mt * 16 + lg * 4;
                st4(t1, j, gb, f2b(acc[m][n][0]), f2b(acc[m][n][1]),
                               f2b(acc[m][n][2]), f2b(acc[m][n][3]));
            } else {
                int cb = (mt - 4) * 16 + lg * 4;
#pragma unroll
                for (int r = 0; r < 4; ++r)
                    st1(t2, cb + r, j, f2b(acc[m][n][r]));
            }
        }
    }
    __syncthreads();

    // ---- GEMM2: S[i][j] = sum_g XT[i][g] T[j][g]  (= X^T G X, scale folded in G)
    f32x4 s4[4];
#pragma unroll
    for (int n = 0; n < 4; ++n) s4[n] = fz;
#pragma unroll
    for (int ks = 0; ks < 2; ++ks) {
        bf16x8 aq = ld8(t0, wid * 16 + lr, ks * 32 + lg * 8);
#pragma unroll
        for (int n = 0; n < 4; ++n) {
            bf16x8 bt = ld8(t1, n * 16 + lr, ks * 32 + lg * 8);
            s4[n] = __builtin_amdgcn_mfma_f32_16x16x32_bf16(aq, bt, s4[n], 0, 0, 0);
        }
    }

    // ---- register softmax (16-lane lr-group holds a row across n), write P into t0.
    // No barrier needed: wave wid reads/writes ONLY t0 rows [wid*16, wid*16+16).
#pragma unroll
    for (int r = 0; r < 4; ++r) {
        const int i = wid * 16 + lg * 4 + r;
        float v[4], mx = -1e30f;
#pragma unroll
        for (int n = 0; n < 4; ++n) {
            v[n] = s4[n][r];
            int j = n * 16 + lr;
            mx = fmaxf(mx, (j < NPIX) ? v[n] : -1e30f);
        }
        mx = fmaxf(mx, __shfl_xor(mx, 1));
        mx = fmaxf(mx, __shfl_xor(mx, 2));
        mx = fmaxf(mx, __shfl_xor(mx, 4));
        mx = fmaxf(mx, __shfl_xor(mx, 8));
        float e[4], sm = 0.f;
#pragma unroll
        for (int n = 0; n < 4; ++n) {
            int j = n * 16 + lr;
            e[n] = (j < NPIX) ? __expf(v[n] - mx) : 0.f;
            sm += e[n];
        }
        sm += __shfl_xor(sm, 1);
        sm += __shfl_xor(sm, 2);
        sm += __shfl_xor(sm, 4);
        sm += __shfl_xor(sm, 8);
        float sinv = 1.0f / sm;
#pragma unroll
        for (int n = 0; n < 4; ++n)
            st1(t0, i, n * 16 + lr, f2b(e[n] * sinv));
    }
    __syncthreads();

    // ---- GEMM3: Y[co][p] = sum_j F[co][j] P[p][j]
    f32x4 y4[4];
#pragma unroll
    for (int n = 0; n < 4; ++n) y4[n] = fz;
#pragma unroll
    for (int ks = 0; ks < 2; ++ks) {
        bf16x8 af = ld8(t2, wid * 16 + lr, ks * 32 + lg * 8);
#pragma unroll
        for (int n = 0; n < 4; ++n) {
            bf16x8 bp = ld8(t0, n * 16 + lr, ks * 32 + lg * 8);
            y4[n] = __builtin_amdgcn_mfma_f32_16x16x32_bf16(af, bp, y4[n], 0, 0, 0);
        }
    }

    const int cb = wid * 16 + lg * 4;
    float bias[4];
#pragma unroll
    for (int r = 0; r < 4; ++r) bias[r] = (cb + r < CIN) ? bproj[cb + r] : 0.f;
#pragma unroll
    for (int n = 0; n < 4; ++n) {
        int p = n * 16 + lr;
        if (p < NPIX) {
            int dh = p / 7, dw = p - dh * 7;
            int h = h0 + dh, w = w0 + dw;
#pragma unroll
            for (int r = 0; r < 4; ++r) {
                int co = cb + r;
                if (co < CIN)
                    out[((b * CIN + co) * HW + h) * HW + w] = y4[n][r] + bias[r];
            }
        }
    }
}

extern "C" void kernel_launch(void* const* d_in, const int* in_sizes, int n_in,
                              void* d_out, int out_size, void* d_ws, size_t ws_size,
                              hipStream_t stream) {
    const float* x    = (const float*)d_in[0];
    const float* wqkv = (const float*)d_in[1];
    const float* wp   = (const float*)d_in[2];
    const float* bp   = (const float*)d_in[3];
    float* out = (float*)d_out;

    u16* wb = (u16*)d_ws;   // 128*64 bf16: [G = Wq^T Wk /8 ; Wf = Wp Wv]

    prep_weights<<<32, 256, 0, stream>>>(wqkv, wp, wb);
    win_attn<<<8192, 256, 0, stream>>>(x, wb, bp, out);
}